// Round 6
// baseline (1360.808 us; speedup 1.0000x reference)
//
#include <hip/hip_runtime.h>

#define DEV_INLINE __device__ __forceinline__

DEV_INLINE void fma4(float4& a, float s, const float4& w) {
  a.x = fmaf(s, w.x, a.x);
  a.y = fmaf(s, w.y, a.y);
  a.z = fmaf(s, w.z, a.z);
  a.w = fmaf(s, w.w, a.w);
}

DEV_INLINE float4 xform4(const float4& v, const float4& sc, const float4& sh) {
  float4 r;
  r.x = fmaxf(fmaf(v.x, sc.x, sh.x), 0.f);
  r.y = fmaxf(fmaf(v.y, sc.y, sh.y), 0.f);
  r.z = fmaxf(fmaf(v.z, sc.z, sh.z), 0.f);
  r.w = fmaxf(fmaf(v.w, sc.w, sh.w), 0.f);
  return r;
}

// HW float atomic (global_atomic_add_f32); targets in d_ws (coarse-grained).
DEV_INLINE void atomAddF(float* p, float v) { unsafeAtomicAdd(p, v); }

// ======================= CSR build (once per launch; ~4 MB scratch) ==========
__global__ void hist_kernel(const int* __restrict__ dst, int* __restrict__ deg, int E) {
  int i = blockIdx.x * blockDim.x + threadIdx.x;
  int st = gridDim.x * blockDim.x;
  for (; i < E; i += st) atomicAdd(&deg[dst[i]], 1);
}

// single-block exclusive scan: deg[N] -> rowStart[N+1], cursor[N]
__global__ __launch_bounds__(1024) void scan_kernel(const int* __restrict__ deg,
                                                    int* __restrict__ rowStart,
                                                    int* __restrict__ cursor, int N) {
  __shared__ int part[1024];
  const int t = threadIdx.x;
  const int chunk = (N + 1023) / 1024;
  const int base = t * chunk;
  int s = 0;
  for (int i = 0; i < chunk; ++i) {
    int idx = base + i;
    if (idx < N) s += deg[idx];
  }
  part[t] = s;
  __syncthreads();
  for (int off = 1; off < 1024; off <<= 1) {
    int u = (t >= off) ? part[t - off] : 0;
    __syncthreads();
    part[t] += u;
    __syncthreads();
  }
  int running = part[t] - s;  // exclusive offset for this thread's chunk
  for (int i = 0; i < chunk; ++i) {
    int idx = base + i;
    if (idx < N) {
      rowStart[idx] = running;
      cursor[idx] = running;
      running += deg[idx];
    }
  }
  if (t == 1023) rowStart[N] = part[1023];
}

__global__ void fill_kernel(const int* __restrict__ src, const int* __restrict__ dst,
                            int* __restrict__ cursor, int* __restrict__ adj, int E) {
  int i = blockIdx.x * blockDim.x + threadIdx.x;
  int st = gridDim.x * blockDim.x;
  for (; i < E; i += st) {
    int slot = atomicAdd(&cursor[dst[i]], 1);
    adj[slot] = src[i];
  }
}

// ================= GIN aggregation via CSR gather (atomic-free) ==============
// agg[n] = xform?(h[n]) + sum_{e in in(n)} xform?(h[adj[e]])
template <int CH4, bool XF>  // CH4 = H/4
__global__ __launch_bounds__(256) void gather_kernel(const float* __restrict__ h,
                                                     const int* __restrict__ rowStart,
                                                     const int* __restrict__ adj,
                                                     const float* __restrict__ ss,
                                                     float* __restrict__ agg, int N) {
  constexpr int H = CH4 * 4;
  constexpr int NPB = 256 / CH4;
  const int t = threadIdx.x;
  const int c4 = t % CH4;  // pow2 -> and
  const int nl = t / CH4;  // pow2 -> shift
  const int node = blockIdx.x * NPB + nl;
  if (node >= N) return;
  const int c = c4 * 4;
  float4 sc, sh;
  if (XF) {
    sc = *reinterpret_cast<const float4*>(ss + c);
    sh = *reinterpret_cast<const float4*>(ss + H + c);
  }
  float4 acc = *reinterpret_cast<const float4*>(h + (long long)node * H + c);
  if (XF) acc = xform4(acc, sc, sh);
  const int e1 = rowStart[node + 1];
  int i = rowStart[node];
  // unroll-2: keep two gather rows in flight (latency overlap)
  for (; i + 1 < e1; i += 2) {
    int s0 = adj[i], s1 = adj[i + 1];
    float4 u0 = *reinterpret_cast<const float4*>(h + (long long)s0 * H + c);
    float4 u1 = *reinterpret_cast<const float4*>(h + (long long)s1 * H + c);
    if (XF) { u0 = xform4(u0, sc, sh); u1 = xform4(u1, sc, sh); }
    acc.x += u0.x + u1.x; acc.y += u0.y + u1.y;
    acc.z += u0.z + u1.z; acc.w += u0.w + u1.w;
  }
  if (i < e1) {
    int s0 = adj[i];
    float4 u0 = *reinterpret_cast<const float4*>(h + (long long)s0 * H + c);
    if (XF) u0 = xform4(u0, sc, sh);
    acc.x += u0.x; acc.y += u0.y; acc.z += u0.z; acc.w += u0.w;
  }
  *reinterpret_cast<float4*>(agg + (long long)node * H + c) = acc;
}

// ------------------------------------------------- main GEMM: out = act(A@W + b)
// BM=64 x BN=128 per 256-thread block; K chunked by 64 via LDS.
// __launch_bounds__(256,3): 3 waves/EU -> VGPR cap ~170; `#pragma unroll 1`
// on the kc loop prevents the full-unroll software-pipeline VGPR blowup
// (round-4 counters: VGPR=256, Occupancy 9%, VALUBusy 13% on K=128 variants).
template <int K, int NC, bool RELU, bool STATS>
__global__ __launch_bounds__(256, 3) void gemm_kernel(const float* __restrict__ A,
                                                      const float* __restrict__ W,
                                                      const float* __restrict__ bias,
                                                      float* __restrict__ out,
                                                      float* __restrict__ stats, int N) {
  __shared__ float As[64 * 68];   // 64 rows x 64 k, padded stride 68 (float4-aligned)
  __shared__ float Ws[64 * 128];  // 64 k x 128 cols
  const int t = threadIdx.x;
  const int tx = t & 31, ty = t >> 5;
  const int row0 = blockIdx.x * 64;
  const int col0 = blockIdx.y * 128;

  float4 acc[8];
#pragma unroll
  for (int i = 0; i < 8; ++i) acc[i] = make_float4(0.f, 0.f, 0.f, 0.f);

#pragma unroll 1
  for (int kc = 0; kc < K; kc += 64) {
    __syncthreads();
#pragma unroll
    for (int p = 0; p < 4; ++p) {  // A chunk: 64x64 floats = 1024 float4
      int s = p * 256 + t;
      int r = s >> 4, kq = (s & 15) << 2;
      float4 v = make_float4(0.f, 0.f, 0.f, 0.f);
      if (row0 + r < N)
        v = *reinterpret_cast<const float4*>(A + (long long)(row0 + r) * K + kc + kq);
      *reinterpret_cast<float4*>(As + r * 68 + kq) = v;
    }
#pragma unroll
    for (int p = 0; p < 8; ++p) {  // W chunk: 64x128 floats = 2048 float4
      int s = p * 256 + t;
      int k = s >> 5, c = (s & 31) << 2;
      *reinterpret_cast<float4*>(Ws + k * 128 + c) =
          *reinterpret_cast<const float4*>(W + (long long)(kc + k) * NC + col0 + c);
    }
    __syncthreads();
#pragma unroll
    for (int k4 = 0; k4 < 16; ++k4) {
      float4 w0 = *reinterpret_cast<const float4*>(Ws + (k4 * 4 + 0) * 128 + tx * 4);
      float4 w1 = *reinterpret_cast<const float4*>(Ws + (k4 * 4 + 1) * 128 + tx * 4);
      float4 w2 = *reinterpret_cast<const float4*>(Ws + (k4 * 4 + 2) * 128 + tx * 4);
      float4 w3 = *reinterpret_cast<const float4*>(Ws + (k4 * 4 + 3) * 128 + tx * 4);
#pragma unroll
      for (int i = 0; i < 8; ++i) {
        float4 a = *reinterpret_cast<const float4*>(As + (ty * 8 + i) * 68 + k4 * 4);
        fma4(acc[i], a.x, w0);
        fma4(acc[i], a.y, w1);
        fma4(acc[i], a.z, w2);
        fma4(acc[i], a.w, w3);
      }
    }
  }

  const float4 b4 = *reinterpret_cast<const float4*>(bias + col0 + tx * 4);
  float ps[4] = {0.f, 0.f, 0.f, 0.f}, pq[4] = {0.f, 0.f, 0.f, 0.f};
#pragma unroll
  for (int i = 0; i < 8; ++i) {
    int row = row0 + ty * 8 + i;
    float4 v = acc[i];
    v.x += b4.x; v.y += b4.y; v.z += b4.z; v.w += b4.w;
    if (RELU) {
      v.x = fmaxf(v.x, 0.f); v.y = fmaxf(v.y, 0.f);
      v.z = fmaxf(v.z, 0.f); v.w = fmaxf(v.w, 0.f);
    }
    if (row < N) {
      *reinterpret_cast<float4*>(out + (long long)row * NC + col0 + tx * 4) = v;
      if (STATS) {
        ps[0] += v.x; ps[1] += v.y; ps[2] += v.z; ps[3] += v.w;
        pq[0] += v.x * v.x; pq[1] += v.y * v.y; pq[2] += v.z * v.z; pq[3] += v.w * v.w;
      }
    }
  }
  if (STATS) {
    __syncthreads();  // As no longer read; reuse as reduction scratch
    float* r1 = As;
    float* r2 = As + 1024;
#pragma unroll
    for (int j = 0; j < 4; ++j) {
      r1[ty * 128 + tx * 4 + j] = ps[j];
      r2[ty * 128 + tx * 4 + j] = pq[j];
    }
    __syncthreads();
    if (t < 128) {
      float s = 0.f, s2 = 0.f;
#pragma unroll
      for (int q = 0; q < 8; ++q) { s += r1[q * 128 + t]; s2 += r2[q * 128 + t]; }
      atomAddF(&stats[col0 + t], s);
      atomAddF(&stats[NC + col0 + t], s2);
    }
  }
}

// ------------------------------------------------- BN finalize: fold to scale/shift
__global__ void bn_finalize_kernel(const float* __restrict__ stats, const float* __restrict__ g,
                                   const float* __restrict__ b, float* __restrict__ ss, int C,
                                   float invN) {
  int c = blockIdx.x * blockDim.x + threadIdx.x;
  if (c < C) {
    float mean = stats[c] * invN;
    float var = stats[C + c] * invN - mean * mean;
    float rstd = rsqrtf(var + 1e-5f);
    float scale = g[c] * rstd;
    ss[c] = scale;
    ss[C + c] = b[c] - mean * scale;
  }
}

// --------------------------- per-graph add-pool of xform?(h), row-sliced
// grid (256, S); each slice-block covers rows rs+rp+slice*RPG :: RPG*S.
// Partial results combined via HW fp32 atomics into zero-initialized pooled.
template <int C, bool XF, int S>
__global__ void pool_kernel(const float* __restrict__ h, const int* __restrict__ batch,
                            const float* __restrict__ ss, float* __restrict__ pooled, int N,
                            int colOff) {
  constexpr int CH4 = C / 4;
  constexpr int RPG = 256 / CH4;
  const int g = blockIdx.x;
  const int slice = blockIdx.y;
  const int t = threadIdx.x;
  // rs = lower_bound(batch, g), re = upper_bound(batch, g)  (batch sorted)
  int lo = 0, hi = N;
  while (lo < hi) { int m = (lo + hi) >> 1; if (batch[m] < g) lo = m + 1; else hi = m; }
  const int rs = lo;
  hi = N;
  while (lo < hi) { int m = (lo + hi) >> 1; if (batch[m] <= g) lo = m + 1; else hi = m; }
  const int re = lo;

  const int c = (t % CH4) * 4;
  const int rp = t / CH4;
  float4 sc, sh;
  if (XF) {
    sc = *reinterpret_cast<const float4*>(ss + c);
    sh = *reinterpret_cast<const float4*>(ss + C + c);
  }
  float4 acc = make_float4(0.f, 0.f, 0.f, 0.f);
  for (int r = rs + rp + slice * RPG; r < re; r += RPG * S) {
    float4 v = *reinterpret_cast<const float4*>(h + (long long)r * C + c);
    if (XF) v = xform4(v, sc, sh);
    acc.x += v.x; acc.y += v.y; acc.z += v.z; acc.w += v.w;
  }
  __shared__ float4 red[256];
  red[t] = acc;
  __syncthreads();
  if (t < CH4) {
    float4 s = red[t];
#pragma unroll
    for (int q = 1; q < RPG; ++q) {
      float4 v = red[q * CH4 + t];
      s.x += v.x; s.y += v.y; s.z += v.z; s.w += v.w;
    }
    float* p = pooled + g * 768 + colOff + t * 4;
    atomAddF(p + 0, s.x);
    atomAddF(p + 1, s.y);
    atomAddF(p + 2, s.z);
    atomAddF(p + 3, s.w);
  }
}

// ------------------------------------------------- small-M readout GEMM
template <bool RELU>
__global__ __launch_bounds__(256) void small_gemm_kernel(const float* __restrict__ A,
                                                         const float* __restrict__ W,
                                                         const float* __restrict__ bias,
                                                         float* __restrict__ out, int K, int NC) {
  const int t = threadIdx.x;
  const int tx = t & 15, rl = t >> 4;
  const int row = blockIdx.x * 16 + rl;
  const int col = blockIdx.y * 64 + tx * 4;
  const float* a = A + (long long)row * K;
  const float* w = W + col;
  float4 acc = make_float4(0.f, 0.f, 0.f, 0.f);
  for (int k = 0; k < K; k += 4) {
    float4 a4 = *reinterpret_cast<const float4*>(a + k);
    float4 w0 = *reinterpret_cast<const float4*>(w + (long long)(k + 0) * NC);
    float4 w1 = *reinterpret_cast<const float4*>(w + (long long)(k + 1) * NC);
    float4 w2 = *reinterpret_cast<const float4*>(w + (long long)(k + 2) * NC);
    float4 w3 = *reinterpret_cast<const float4*>(w + (long long)(k + 3) * NC);
    fma4(acc, a4.x, w0);
    fma4(acc, a4.y, w1);
    fma4(acc, a4.z, w2);
    fma4(acc, a4.w, w3);
  }
  float4 b4 = *reinterpret_cast<const float4*>(bias + col);
  acc.x += b4.x; acc.y += b4.y; acc.z += b4.z; acc.w += b4.w;
  if (RELU) {
    acc.x = fmaxf(acc.x, 0.f); acc.y = fmaxf(acc.y, 0.f);
    acc.z = fmaxf(acc.z, 0.f); acc.w = fmaxf(acc.w, 0.f);
  }
  *reinterpret_cast<float4*>(out + (long long)row * NC + col) = acc;
}

static inline int imin_(int a, int b) { return a < b ? a : b; }
static inline int cdiv_(long long a, long long b) { return (int)((a + b - 1) / b); }

extern "C" void kernel_launch(void* const* d_in, const int* in_sizes, int n_in,
                              void* d_out, int out_size, void* d_ws, size_t ws_size,
                              hipStream_t stream) {
  const int N = in_sizes[0] / 64;
  const int E = in_sizes[1] / 2;
  const float* x = (const float*)d_in[0];
  const int* ei = (const int*)d_in[1];
  const int* batch = (const int*)d_in[2];
  const float *w1a = (const float*)d_in[3], *b1a = (const float*)d_in[4];
  const float *w1b = (const float*)d_in[5], *b1b = (const float*)d_in[6];
  const float *g1 = (const float*)d_in[7], *bt1 = (const float*)d_in[8];
  const float *w2a = (const float*)d_in[9], *b2a = (const float*)d_in[10];
  const float *w2b = (const float*)d_in[11], *b2b = (const float*)d_in[12];
  const float *g2 = (const float*)d_in[13], *bt2 = (const float*)d_in[14];
  const float *w3 = (const float*)d_in[15], *b3 = (const float*)d_in[16];
  const float *g3 = (const float*)d_in[17], *bt3 = (const float*)d_in[18];
  const float *wl1 = (const float*)d_in[19], *bl1 = (const float*)d_in[20];
  const float *wl2 = (const float*)d_in[21], *bl2 = (const float*)d_in[22];
  const int* src = ei;
  const int* dst = ei + E;

  float* ws = (float*)d_ws;
  float* buf0 = ws;                            // N*128
  float* buf1 = buf0 + (size_t)N * 128;        // N*128
  float* buf2 = buf1 + (size_t)N * 128;        // N*128 (raw pre-BN layer outputs)
  float* buf3 = buf2 + (size_t)N * 128;        // N*512 (raw z3; CSR overlaid pre-write)
  float* pooled = buf3 + (size_t)N * 512;      // 256*768
  float* l1 = pooled + 256 * 768;              // 256*1024
  float* sums = l1 + 256 * 1024;               // 1536: [s1(256) s2(256) s3(1024)]
  float* ssb = sums + 1536;                    // 1536: folded BN scale/shift

  // CSR scratch overlaid on buf3: dead before the layer-3 GEMM writes buf3.
  int* rowStart = (int*)buf3;                  // N+1
  int* cursor = rowStart + (N + 1);            // N
  int* adj = cursor + N;                       // E
  int* deg = adj + E;                          // N

  hipMemsetAsync(sums, 0, 1536 * sizeof(float), stream);
  hipMemsetAsync(deg, 0, (size_t)N * sizeof(int), stream);
  hipMemsetAsync(pooled, 0, 256 * 768 * sizeof(float), stream);

  const int NB = (N + 63) / 64;
  const float invN = 1.0f / (float)N;
  float* ss1 = ssb;         // 128 scale + 128 shift
  float* ss2 = ssb + 256;   // 128 + 128
  float* ss3 = ssb + 512;   // 512 + 512

  // ---------- CSR build (shared by all 3 layers)
  hist_kernel<<<imin_(cdiv_(E, 256), 8192), 256, 0, stream>>>(dst, deg, E);
  scan_kernel<<<1, 1024, 0, stream>>>(deg, rowStart, cursor, N);
  fill_kernel<<<imin_(cdiv_(E, 256), 8192), 256, 0, stream>>>(src, dst, cursor, adj, E);

  // ---------- layer 1: z1 = relu(agg(x)@w1a+b1a)@w1b+b1b  (raw, pre-BN)
  gather_kernel<16, false><<<cdiv_(N, 16), 256, 0, stream>>>(x, rowStart, adj, nullptr, buf0, N);
  gemm_kernel<64, 128, true, false><<<dim3(NB, 1), 256, 0, stream>>>(buf0, w1a, b1a, buf1, nullptr, N);
  gemm_kernel<128, 128, false, true><<<dim3(NB, 1), 256, 0, stream>>>(buf1, w1b, b1b, buf2, sums, N);
  bn_finalize_kernel<<<1, 128, 0, stream>>>(sums, g1, bt1, ss1, 128, invN);
  // h1 = relu(bn1(z1)) never materialized: ss1 folded into pool/gather consumers.
  pool_kernel<128, true, 4><<<dim3(256, 4), 256, 0, stream>>>(buf2, batch, ss1, pooled, N, 0);

  // ---------- layer 2: z2 (raw) from agg(h1); h1 applied on the fly from buf2+ss1
  gather_kernel<32, true><<<cdiv_(N, 8), 256, 0, stream>>>(buf2, rowStart, adj, ss1, buf1, N);
  gemm_kernel<128, 128, true, false><<<dim3(NB, 1), 256, 0, stream>>>(buf1, w2a, b2a, buf0, nullptr, N);
  gemm_kernel<128, 128, false, true><<<dim3(NB, 1), 256, 0, stream>>>(buf0, w2b, b2b, buf2, sums + 256, N);
  bn_finalize_kernel<<<1, 128, 0, stream>>>(sums + 256, g2, bt2, ss2, 128, invN);
  pool_kernel<128, true, 4><<<dim3(256, 4), 256, 0, stream>>>(buf2, batch, ss2, pooled, N, 128);

  // ---------- layer 3: z3 = relu(agg(h2)@w3+b3); h2 applied on the fly from buf2+ss2
  gather_kernel<32, true><<<cdiv_(N, 8), 256, 0, stream>>>(buf2, rowStart, adj, ss2, buf1, N);
  // (CSR arrays dead from here; the next GEMM overwrites buf3.)
  gemm_kernel<128, 512, true, true><<<dim3(NB, 4), 256, 0, stream>>>(buf1, w3, b3, buf3, sums + 512, N);
  bn_finalize_kernel<<<1, 512, 0, stream>>>(sums + 512, g3, bt3, ss3, 512, invN);
  pool_kernel<512, true, 8><<<dim3(256, 8), 256, 0, stream>>>(buf3, batch, ss3, pooled, N, 256);

  // ---------- readout: out = relu(pooled@wl1+bl1)@wl2+bl2
  small_gemm_kernel<true><<<dim3(16, 16), 256, 0, stream>>>(pooled, wl1, bl1, l1, 768, 1024);
  small_gemm_kernel<false><<<dim3(16, 4), 256, 0, stream>>>(l1, wl2, bl2, (float*)d_out, 1024, 256);
}

// Round 15
// 903.293 us; speedup vs baseline: 1.5065x; 1.5065x over previous
//
#include <hip/hip_runtime.h>

#define DEV_INLINE __device__ __forceinline__

typedef __attribute__((ext_vector_type(8))) short short8v;   // 8 bf16 (4 VGPR)
typedef __attribute__((ext_vector_type(4))) float f32x4;     // MFMA C/D

DEV_INLINE void fma4(float4& a, float s, const float4& w) {
  a.x = fmaf(s, w.x, a.x);
  a.y = fmaf(s, w.y, a.y);
  a.z = fmaf(s, w.z, a.z);
  a.w = fmaf(s, w.w, a.w);
}

DEV_INLINE float4 xform4(const float4& v, const float4& sc, const float4& sh) {
  float4 r;
  r.x = fmaxf(fmaf(v.x, sc.x, sh.x), 0.f);
  r.y = fmaxf(fmaf(v.y, sc.y, sh.y), 0.f);
  r.z = fmaxf(fmaf(v.z, sc.z, sh.z), 0.f);
  r.w = fmaxf(fmaf(v.w, sc.w, sh.w), 0.f);
  return r;
}

DEV_INLINE unsigned short f2bf(float f) {  // RNE float->bf16
  unsigned int u = __float_as_uint(f);
  u += 0x7FFFu + ((u >> 16) & 1u);
  return (unsigned short)(u >> 16);
}

// HW float atomic (global_atomic_add_f32); targets in d_ws (coarse-grained).
DEV_INLINE void atomAddF(float* p, float v) { unsafeAtomicAdd(p, v); }

// ======================= CSR build (once per launch) =========================
__global__ void hist_kernel(const int* __restrict__ dst, int* __restrict__ deg, int E) {
  int i = blockIdx.x * blockDim.x + threadIdx.x;
  int st = gridDim.x * blockDim.x;
  for (; i < E; i += st) atomicAdd(&deg[dst[i]], 1);
}

__global__ __launch_bounds__(1024) void scan_kernel(const int* __restrict__ deg,
                                                    int* __restrict__ rowStart,
                                                    int* __restrict__ cursor, int N) {
  __shared__ int part[1024];
  const int t = threadIdx.x;
  const int chunk = (N + 1023) / 1024;
  const int base = t * chunk;
  int s = 0;
  for (int i = 0; i < chunk; ++i) {
    int idx = base + i;
    if (idx < N) s += deg[idx];
  }
  part[t] = s;
  __syncthreads();
  for (int off = 1; off < 1024; off <<= 1) {
    int u = (t >= off) ? part[t - off] : 0;
    __syncthreads();
    part[t] += u;
    __syncthreads();
  }
  int running = part[t] - s;
  for (int i = 0; i < chunk; ++i) {
    int idx = base + i;
    if (idx < N) {
      rowStart[idx] = running;
      cursor[idx] = running;
      running += deg[idx];
    }
  }
  if (t == 1023) rowStart[N] = part[1023];
}

__global__ void fill_kernel(const int* __restrict__ src, const int* __restrict__ dst,
                            int* __restrict__ cursor, int* __restrict__ adj, int E) {
  int i = blockIdx.x * blockDim.x + threadIdx.x;
  int st = gridDim.x * blockDim.x;
  for (; i < E; i += st) {
    int slot = atomicAdd(&cursor[dst[i]], 1);
    adj[slot] = src[i];
  }
}

// ================= GIN aggregation via CSR gather (atomic-free) ==============
template <int CH4, bool XF>  // CH4 = H/4
__global__ __launch_bounds__(256) void gather_kernel(const float* __restrict__ h,
                                                     const int* __restrict__ rowStart,
                                                     const int* __restrict__ adj,
                                                     const float* __restrict__ ss,
                                                     float* __restrict__ agg, int N) {
  constexpr int H = CH4 * 4;
  constexpr int NPB = 256 / CH4;
  const int t = threadIdx.x;
  const int c4 = t % CH4;
  const int nl = t / CH4;
  const int node = blockIdx.x * NPB + nl;
  if (node >= N) return;
  const int c = c4 * 4;
  float4 sc, sh;
  if (XF) {
    sc = *reinterpret_cast<const float4*>(ss + c);
    sh = *reinterpret_cast<const float4*>(ss + H + c);
  }
  float4 acc = *reinterpret_cast<const float4*>(h + (long long)node * H + c);
  if (XF) acc = xform4(acc, sc, sh);
  const int e1 = rowStart[node + 1];
  int i = rowStart[node];
  for (; i + 1 < e1; i += 2) {
    int s0 = adj[i], s1 = adj[i + 1];
    float4 u0 = *reinterpret_cast<const float4*>(h + (long long)s0 * H + c);
    float4 u1 = *reinterpret_cast<const float4*>(h + (long long)s1 * H + c);
    if (XF) { u0 = xform4(u0, sc, sh); u1 = xform4(u1, sc, sh); }
    acc.x += u0.x + u1.x; acc.y += u0.y + u1.y;
    acc.z += u0.z + u1.z; acc.w += u0.w + u1.w;
  }
  if (i < e1) {
    int s0 = adj[i];
    float4 u0 = *reinterpret_cast<const float4*>(h + (long long)s0 * H + c);
    if (XF) u0 = xform4(u0, sc, sh);
    acc.x += u0.x; acc.y += u0.y; acc.z += u0.z; acc.w += u0.w;
  }
  *reinterpret_cast<float4*>(agg + (long long)node * H + c) = acc;
}

// ============== weight prep: Wbf[((k>>3)*NC + c)*8 + (k&7)] = bf16(W[k][c]) ==
// Fragment-contiguous layout: a B-frag (col c, k-block kb) is one 16B load.
template <int K, int NC>
__global__ void wprep_kernel(const float* __restrict__ W, unsigned short* __restrict__ Wbf) {
  int i = blockIdx.x * blockDim.x + threadIdx.x;  // over (K/8)*NC groups
  if (i >= (K / 8) * NC) return;
  int kb = i / NC, c = i % NC;  // NC pow2 -> shifts
  union { ushort4 u4[2]; unsigned short u[8]; } pk;
#pragma unroll
  for (int j = 0; j < 8; ++j) pk.u[j] = f2bf(W[(long long)(kb * 8 + j) * NC + c]);
  *reinterpret_cast<ushort4*>(Wbf + (long long)i * 8) = pk.u4[0];
  *reinterpret_cast<ushort4*>(Wbf + (long long)i * 8 + 4) = pk.u4[1];
}

// ======================= MFMA bf16 GEMM: out = act(A@W + b) ==================
// 256 threads = 4 waves (2x2); block tile 128x128; wave tile 64x64 = 4x4 frags
// of mfma_f32_16x16x32_bf16. A read directly from global (fp32->bf16 cvt in
// regs; 16 rows x 128B fully-coalesced per frag-group). B from prepped Wbf
// (one 16B load per frag, L2-resident). No LDS.
// Frag maps (guide §3, m89-verified): A: row=lane&15, k=8*(lane>>4)+j;
// B: col=lane&15, same k; C/D: col=lane&15, row=4*(lane>>4)+reg.
template <int K, int NC, bool RELU, bool STATS>
__global__ __launch_bounds__(256) void mgemm_kernel(const float* __restrict__ A,
                                                    const unsigned short* __restrict__ Wbf,
                                                    const float* __restrict__ bias,
                                                    float* __restrict__ out,
                                                    float* __restrict__ stats, int N) {
  const int t = threadIdx.x;
  const int lane = t & 63;
  const int w = t >> 6;
  const int wr = w >> 1, wc = w & 1;
  const int brow = blockIdx.x * 128 + wr * 64;
  const int bcol = blockIdx.y * 128 + wc * 64;
  const int l16 = lane & 15, lq = lane >> 4;

  f32x4 acc[4][4] = {};

  for (int k0 = 0; k0 < K; k0 += 32) {
    short8v a[4], b[4];
#pragma unroll
    for (int m = 0; m < 4; ++m) {
      int row = brow + m * 16 + l16;
      float4 lo = make_float4(0.f, 0.f, 0.f, 0.f), hi = lo;
      if (row < N) {
        const float* ap = A + (long long)row * K + k0 + lq * 8;
        lo = *reinterpret_cast<const float4*>(ap);
        hi = *reinterpret_cast<const float4*>(ap + 4);
      }
      union { short8v v; unsigned short u[8]; } pk;
      pk.u[0] = f2bf(lo.x); pk.u[1] = f2bf(lo.y); pk.u[2] = f2bf(lo.z); pk.u[3] = f2bf(lo.w);
      pk.u[4] = f2bf(hi.x); pk.u[5] = f2bf(hi.y); pk.u[6] = f2bf(hi.z); pk.u[7] = f2bf(hi.w);
      a[m] = pk.v;
    }
    const int kb = (k0 >> 3) + lq;
#pragma unroll
    for (int n = 0; n < 4; ++n) {
      int col = bcol + n * 16 + l16;
      b[n] = *reinterpret_cast<const short8v*>(Wbf + ((long long)kb * NC + col) * 8);
    }
#pragma unroll
    for (int m = 0; m < 4; ++m)
#pragma unroll
      for (int n = 0; n < 4; ++n)
        acc[m][n] = __builtin_amdgcn_mfma_f32_16x16x32_bf16(a[m], b[n], acc[m][n], 0, 0, 0);
  }

  float ps[4] = {0.f, 0.f, 0.f, 0.f}, pq[4] = {0.f, 0.f, 0.f, 0.f};
#pragma unroll
  for (int n = 0; n < 4; ++n) {
    int col = bcol + n * 16 + l16;
    float bv = bias[col];
#pragma unroll
    for (int m = 0; m < 4; ++m) {
#pragma unroll
      for (int j = 0; j < 4; ++j) {
        int row = brow + m * 16 + lq * 4 + j;
        float v = acc[m][n][j] + bv;
        if (RELU) v = fmaxf(v, 0.f);
        if (row < N) {
          out[(long long)row * NC + col] = v;
          if (STATS) { ps[n] += v; pq[n] += v * v; }
        }
      }
    }
  }
  if (STATS) {
#pragma unroll
    for (int n = 0; n < 4; ++n) {
      float s = ps[n], q = pq[n];
      s += __shfl_xor(s, 16); q += __shfl_xor(q, 16);
      s += __shfl_xor(s, 32); q += __shfl_xor(q, 32);
      if (lane < 16) {
        int col = bcol + n * 16 + lane;
        atomAddF(&stats[col], s);
        atomAddF(&stats[NC + col], q);
      }
    }
  }
}

// ------------------------------------------------- BN finalize: fold to scale/shift
__global__ void bn_finalize_kernel(const float* __restrict__ stats, const float* __restrict__ g,
                                   const float* __restrict__ b, float* __restrict__ ss, int C,
                                   float invN) {
  int c = blockIdx.x * blockDim.x + threadIdx.x;
  if (c < C) {
    float mean = stats[c] * invN;
    float var = stats[C + c] * invN - mean * mean;
    float rstd = rsqrtf(var + 1e-5f);
    float scale = g[c] * rstd;
    ss[c] = scale;
    ss[C + c] = b[c] - mean * scale;
  }
}

// --------------------------- per-graph add-pool of xform?(h), row-sliced
template <int C, bool XF, int S>
__global__ void pool_kernel(const float* __restrict__ h, const int* __restrict__ batch,
                            const float* __restrict__ ss, float* __restrict__ pooled, int N,
                            int colOff) {
  constexpr int CH4 = C / 4;
  constexpr int RPG = 256 / CH4;
  const int g = blockIdx.x;
  const int slice = blockIdx.y;
  const int t = threadIdx.x;
  int lo = 0, hi = N;
  while (lo < hi) { int m = (lo + hi) >> 1; if (batch[m] < g) lo = m + 1; else hi = m; }
  const int rs = lo;
  hi = N;
  while (lo < hi) { int m = (lo + hi) >> 1; if (batch[m] <= g) lo = m + 1; else hi = m; }
  const int re = lo;

  const int c = (t % CH4) * 4;
  const int rp = t / CH4;
  float4 sc, sh;
  if (XF) {
    sc = *reinterpret_cast<const float4*>(ss + c);
    sh = *reinterpret_cast<const float4*>(ss + C + c);
  }
  float4 acc = make_float4(0.f, 0.f, 0.f, 0.f);
  for (int r = rs + rp + slice * RPG; r < re; r += RPG * S) {
    float4 v = *reinterpret_cast<const float4*>(h + (long long)r * C + c);
    if (XF) v = xform4(v, sc, sh);
    acc.x += v.x; acc.y += v.y; acc.z += v.z; acc.w += v.w;
  }
  __shared__ float4 red[256];
  red[t] = acc;
  __syncthreads();
  if (t < CH4) {
    float4 s = red[t];
#pragma unroll
    for (int q = 1; q < RPG; ++q) {
      float4 v = red[q * CH4 + t];
      s.x += v.x; s.y += v.y; s.z += v.z; s.w += v.w;
    }
    float* p = pooled + g * 768 + colOff + t * 4;
    atomAddF(p + 0, s.x);
    atomAddF(p + 1, s.y);
    atomAddF(p + 2, s.z);
    atomAddF(p + 3, s.w);
  }
}

// ------------------------------------------------- small-M readout GEMM (fp32)
template <bool RELU>
__global__ __launch_bounds__(256) void small_gemm_kernel(const float* __restrict__ A,
                                                         const float* __restrict__ W,
                                                         const float* __restrict__ bias,
                                                         float* __restrict__ out, int K, int NC) {
  const int t = threadIdx.x;
  const int tx = t & 15, rl = t >> 4;
  const int row = blockIdx.x * 16 + rl;
  const int col = blockIdx.y * 64 + tx * 4;
  const float* a = A + (long long)row * K;
  const float* w = W + col;
  float4 acc = make_float4(0.f, 0.f, 0.f, 0.f);
  for (int k = 0; k < K; k += 4) {
    float4 a4 = *reinterpret_cast<const float4*>(a + k);
    float4 w0 = *reinterpret_cast<const float4*>(w + (long long)(k + 0) * NC);
    float4 w1 = *reinterpret_cast<const float4*>(w + (long long)(k + 1) * NC);
    float4 w2 = *reinterpret_cast<const float4*>(w + (long long)(k + 2) * NC);
    float4 w3 = *reinterpret_cast<const float4*>(w + (long long)(k + 3) * NC);
    fma4(acc, a4.x, w0);
    fma4(acc, a4.y, w1);
    fma4(acc, a4.z, w2);
    fma4(acc, a4.w, w3);
  }
  float4 b4 = *reinterpret_cast<const float4*>(bias + col);
  acc.x += b4.x; acc.y += b4.y; acc.z += b4.z; acc.w += b4.w;
  if (RELU) {
    acc.x = fmaxf(acc.x, 0.f); acc.y = fmaxf(acc.y, 0.f);
    acc.z = fmaxf(acc.z, 0.f); acc.w = fmaxf(acc.w, 0.f);
  }
  *reinterpret_cast<float4*>(out + (long long)row * NC + col) = acc;
}

static inline int imin_(int a, int b) { return a < b ? a : b; }
static inline int cdiv_(long long a, long long b) { return (int)((a + b - 1) / b); }

extern "C" void kernel_launch(void* const* d_in, const int* in_sizes, int n_in,
                              void* d_out, int out_size, void* d_ws, size_t ws_size,
                              hipStream_t stream) {
  const int N = in_sizes[0] / 64;
  const int E = in_sizes[1] / 2;
  const float* x = (const float*)d_in[0];
  const int* ei = (const int*)d_in[1];
  const int* batch = (const int*)d_in[2];
  const float *w1a = (const float*)d_in[3], *b1a = (const float*)d_in[4];
  const float *w1b = (const float*)d_in[5], *b1b = (const float*)d_in[6];
  const float *g1 = (const float*)d_in[7], *bt1 = (const float*)d_in[8];
  const float *w2a = (const float*)d_in[9], *b2a = (const float*)d_in[10];
  const float *w2b = (const float*)d_in[11], *b2b = (const float*)d_in[12];
  const float *g2 = (const float*)d_in[13], *bt2 = (const float*)d_in[14];
  const float *w3 = (const float*)d_in[15], *b3 = (const float*)d_in[16];
  const float *g3 = (const float*)d_in[17], *bt3 = (const float*)d_in[18];
  const float *wl1 = (const float*)d_in[19], *bl1 = (const float*)d_in[20];
  const float *wl2 = (const float*)d_in[21], *bl2 = (const float*)d_in[22];
  const int* src = ei;
  const int* dst = ei + E;

  float* ws = (float*)d_ws;
  float* buf0 = ws;                            // N*128
  float* buf1 = buf0 + (size_t)N * 128;        // N*128
  float* buf2 = buf1 + (size_t)N * 128;        // N*128 (raw pre-BN layer outputs)
  float* buf3 = buf2 + (size_t)N * 128;        // N*512 (raw z3; CSR overlaid pre-write)
  float* pooled = buf3 + (size_t)N * 512;      // 256*768
  float* l1 = pooled + 256 * 768;              // 256*1024
  float* sums = l1 + 256 * 1024;               // 1536
  float* ssb = sums + 1536;                    // 1536: folded BN scale/shift
  // bf16 weight buffers (fragment-contiguous), ~123K ushorts total
  unsigned short* wbf1a = (unsigned short*)(ssb + 1536);  // (64/8)*128*8  = 8192
  unsigned short* wbf1b = wbf1a + 8192;                   // (128/8)*128*8 = 16384
  unsigned short* wbf2a = wbf1b + 16384;
  unsigned short* wbf2b = wbf2a + 16384;
  unsigned short* wbf3 = wbf2b + 16384;                   // (128/8)*512*8 = 65536

  // CSR scratch overlaid on buf3: dead before the layer-3 GEMM writes buf3.
  int* rowStart = (int*)buf3;                  // N+1
  int* cursor = rowStart + (N + 1);            // N
  int* adj = cursor + N;                       // E
  int* deg = adj + E;                          // N

  hipMemsetAsync(sums, 0, 1536 * sizeof(float), stream);
  hipMemsetAsync(deg, 0, (size_t)N * sizeof(int), stream);
  hipMemsetAsync(pooled, 0, 256 * 768 * sizeof(float), stream);

  const int NBM = (N + 127) / 128;
  const float invN = 1.0f / (float)N;
  float* ss1 = ssb;
  float* ss2 = ssb + 256;
  float* ss3 = ssb + 512;

  // ---------- weight prep (bf16 fragment layout) + CSR build
  wprep_kernel<64, 128><<<cdiv_(8 * 128, 256), 256, 0, stream>>>(w1a, wbf1a);
  wprep_kernel<128, 128><<<cdiv_(16 * 128, 256), 256, 0, stream>>>(w1b, wbf1b);
  wprep_kernel<128, 128><<<cdiv_(16 * 128, 256), 256, 0, stream>>>(w2a, wbf2a);
  wprep_kernel<128, 128><<<cdiv_(16 * 128, 256), 256, 0, stream>>>(w2b, wbf2b);
  wprep_kernel<128, 512><<<cdiv_(16 * 512, 256), 256, 0, stream>>>(w3, wbf3);
  hist_kernel<<<imin_(cdiv_(E, 256), 8192), 256, 0, stream>>>(dst, deg, E);
  scan_kernel<<<1, 1024, 0, stream>>>(deg, rowStart, cursor, N);
  fill_kernel<<<imin_(cdiv_(E, 256), 8192), 256, 0, stream>>>(src, dst, cursor, adj, E);

  // ---------- layer 1: z1 = relu(agg(x)@w1a+b1a)@w1b+b1b  (raw, pre-BN)
  gather_kernel<16, false><<<cdiv_(N, 16), 256, 0, stream>>>(x, rowStart, adj, nullptr, buf0, N);
  mgemm_kernel<64, 128, true, false><<<dim3(NBM, 1), 256, 0, stream>>>(buf0, wbf1a, b1a, buf1, nullptr, N);
  mgemm_kernel<128, 128, false, true><<<dim3(NBM, 1), 256, 0, stream>>>(buf1, wbf1b, b1b, buf2, sums, N);
  bn_finalize_kernel<<<1, 128, 0, stream>>>(sums, g1, bt1, ss1, 128, invN);
  // h1 = relu(bn1(z1)) never materialized: ss1 folded into pool/gather consumers.
  pool_kernel<128, true, 4><<<dim3(256, 4), 256, 0, stream>>>(buf2, batch, ss1, pooled, N, 0);

  // ---------- layer 2
  gather_kernel<32, true><<<cdiv_(N, 8), 256, 0, stream>>>(buf2, rowStart, adj, ss1, buf1, N);
  mgemm_kernel<128, 128, true, false><<<dim3(NBM, 1), 256, 0, stream>>>(buf1, wbf2a, b2a, buf0, nullptr, N);
  mgemm_kernel<128, 128, false, true><<<dim3(NBM, 1), 256, 0, stream>>>(buf0, wbf2b, b2b, buf2, sums + 256, N);
  bn_finalize_kernel<<<1, 128, 0, stream>>>(sums + 256, g2, bt2, ss2, 128, invN);
  pool_kernel<128, true, 4><<<dim3(256, 4), 256, 0, stream>>>(buf2, batch, ss2, pooled, N, 128);

  // ---------- layer 3
  gather_kernel<32, true><<<cdiv_(N, 8), 256, 0, stream>>>(buf2, rowStart, adj, ss2, buf1, N);
  // (CSR arrays dead from here; the next GEMM overwrites buf3.)
  mgemm_kernel<128, 512, true, true><<<dim3(NBM, 4), 256, 0, stream>>>(buf1, wbf3, b3, buf3, sums + 512, N);
  bn_finalize_kernel<<<1, 512, 0, stream>>>(sums + 512, g3, bt3, ss3, 512, invN);
  pool_kernel<512, true, 8><<<dim3(256, 8), 256, 0, stream>>>(buf3, batch, ss3, pooled, N, 256);

  // ---------- readout: out = relu(pooled@wl1+bl1)@wl2+bl2
  small_gemm_kernel<true><<<dim3(16, 16), 256, 0, stream>>>(pooled, wl1, bl1, l1, 768, 1024);
  small_gemm_kernel<false><<<dim3(16, 4), 256, 0, stream>>>(l1, wl2, bl2, (float*)d_out, 1024, 256);
}